// Round 8
// baseline (192.361 us; speedup 1.0000x reference)
//
#include <hip/hip_runtime.h>
#include <math.h>

#define N_ROWS 8192
#define N_E    16384
#define EDIM   64
#define KSPLIT 16
#define KPER   1024          // codes per split
#define CHUNK  64            // codes per staged chunk
#define NCH    (KPER/CHUNK)  // 16

// Output layout (concatenated flat, all float32):
#define OFF_ZQ    0
#define OFF_LOSS  524288
#define OFF_IDX   524289
#define OFF_NUNIQ 532481
#define OFF_USAGE 532482
#define OFF_TOTAL 548866

typedef __attribute__((ext_vector_type(8)))  short short8;
typedef __attribute__((ext_vector_type(16))) float f32x16;

// hi/lo bf16 split of codebook and z + fp32 transposed z (recomputed every call)
// 3-term scan error <= ~1e-7 (0.05 grid ulp) -- proven safe rounds 4 & 7.
__device__ ushort g_eh[N_E * EDIM];
__device__ ushort g_el[N_E * EDIM];
__device__ ushort g_zh[N_ROWS * EDIM];
__device__ ushort g_zl[N_ROWS * EDIM];
__device__ float  g_zt[N_ROWS * EDIM];   // z transposed: [n][d], for coalesced refine

__device__ __forceinline__ ushort bf16hi(float v) {
    unsigned u = __float_as_uint(v);
    return (ushort)((u + 0x7fffu + ((u >> 16) & 1u)) >> 16);   // RNE
}

// ---------------- kernel 1: hi/lo split of emb & z, anorm, zero side buffers --
__global__ void vq_split(const float* __restrict__ z, const float* __restrict__ emb,
                         float* __restrict__ anorm, float* __restrict__ out,
                         float* __restrict__ lossacc, unsigned* __restrict__ done)
{
    __shared__ float lds[64][129];
    int bid = blockIdx.x, t = threadIdx.x;
    if (bid < 1024) {                       // emb -> g_eh/g_el (float4 vectorized)
        int i = bid * 256 + t;              // 1024*256 float4 = 16384*64 floats
        float4 v = ((const float4*)emb)[i];
        ushort4 h, l;
        h.x = bf16hi(v.x); h.y = bf16hi(v.y);
        h.z = bf16hi(v.z); h.w = bf16hi(v.w);
        l.x = bf16hi(v.x - __uint_as_float((unsigned)h.x << 16));
        l.y = bf16hi(v.y - __uint_as_float((unsigned)h.y << 16));
        l.z = bf16hi(v.z - __uint_as_float((unsigned)h.z << 16));
        l.w = bf16hi(v.w - __uint_as_float((unsigned)h.w << 16));
        ((ushort4*)g_eh)[i] = h;
        ((ushort4*)g_el)[i] = l;
    } else if (bid < 1088) {                // z transpose -> g_zh/g_zl/g_zt + anorm
        int zb = bid - 1024;                // 0..63
        int b = zb >> 3, hw0 = (zb & 7) << 7;
        const float* zp = z + (size_t)b * 65536 + hw0;
        for (int i = 0; i < 32; i++) {
            int j = i * 256 + t;
            int d = j >> 7, hw = j & 127;
            lds[d][hw] = zp[d * 1024 + hw]; // coalesced read
        }
        __syncthreads();
        for (int i = 0; i < 32; i++) {
            int j = i * 256 + t;
            int hw = j >> 6, d = j & 63;    // consecutive t -> consecutive d
            float v = lds[d][hw];
            ushort h = bf16hi(v);
            size_t o = (size_t)(b * 1024 + hw0 + hw) * 64 + d;
            g_zh[o] = h;
            g_zl[o] = bf16hi(v - __uint_as_float((unsigned)h << 16));
            g_zt[o] = v;
        }
        if (t < 128) {                      // anorm: fp32 squares, fp64 sum
            double s = 0.0;
            for (int d = 0; d < 64; d++) {
                float v = lds[d][t];
                s += (double)(v * v);
            }
            anorm[b * 1024 + hw0 + t] = (float)s;
        }
    } else {                                // 1088..1151: zero usage (+scalars)
        int i = (bid - 1088) * 256 + t;
        out[OFF_USAGE + i] = 0.f;
        if (bid == 1088 && t == 0) { *lossacc = 0.f; *done = 0u; }
    }
}

// ---------------- kernel 2: 3-term bf16 MFMA scan, packed-key argmin ----------
// dq = fl(av - 2*(zh.eh + zh.el + zl.eh)): error ~1e-7 << 7.6e-6 grid step.
// KSPLIT=16, CHUNK=64 -> LDS 32 KB/block -> 4 blocks/CU (vs 2 at 64 KB):
// round-7 counters showed no pipe >35% (latency-bound at 2 waves/SIMD).
// Key32 = dq_bits<<6 | slot (slot<32): order-preserving, dq in [2,256).
// pcand entry u32: rel(16) | slot(5) | m(5); rel = dq_ulps - av_ulps + 32768
// (worst |diff| ~2.4e3 << 32767); exact dq reconstruction in refine.
// 32x32x16 layouts (HW-verified rounds 4/7): A[m=lane&31][k=(lane>>5)*8+j];
// B[k][n=lane&31]; C/D col=lane&31, row=(reg&3)+8*(reg>>2)+4*(lane>>5).
__global__ __launch_bounds__(256, 4) void vq_mfma(const float* __restrict__ anorm,
                                                  unsigned* __restrict__ pcand)
{
    // [dbuf][hi/lo][granule g=k/8][code 0..63][8 bf16] = 32 KB; reused as scratch
    __shared__ __align__(16) ushort ebuf[2][2][8][CHUNK][8];

    const int t = threadIdx.x;
    const int w = t >> 6, lane = t & 63;
    const int rb = blockIdx.x >> 4, split = blockIdx.x & 15;
    const int n0 = rb * 128;
    const int nw = n0 + w * 32;
    const int kbase = split * KPER;
    const int m = lane & 31, half = lane >> 5;

    // A fragments (resident whole kernel)
    short8 ah[4], al[4];
#pragma unroll
    for (int ks = 0; ks < 4; ks++) {
        size_t off = (size_t)(nw + m) * 64 + (ks * 2 + half) * 8;
        ah[ks] = *(const short8*)(g_zh + off);
        al[ks] = *(const short8*)(g_zl + off);
    }

    float av[16];
#pragma unroll
    for (int s = 0; s < 16; s++)
        av[s] = anorm[nw + (s & 3) + 8 * (s >> 2) + 4 * half];

    unsigned p1[16], p2[16];
#pragma unroll
    for (int s = 0; s < 16; s++) { p1[s] = 0xFFFFFFFFu; p2[s] = 0xFFFFFFFFu; }

    // async stage: 16 x 1KB per chunk, 4 per wave
    auto stage = [&](int dbuf, int code0) {
#pragma unroll
        for (int jj = 0; jj < 4; jj++) {
            int id = w * 4 + jj;             // 0..15
            int h = id >> 3, g = id & 7;
            const ushort* src = h ? g_el : g_eh;
            const ushort* ga = src + (size_t)(code0 + lane) * 64 + g * 8;
            __builtin_amdgcn_global_load_lds(
                (const __attribute__((address_space(1))) void*)ga,
                (__attribute__((address_space(3))) void*)&ebuf[dbuf][h][g][0][0],
                16, 0, 0);
        }
    };

    stage(0, kbase);
    for (int ch = 0; ch < NCH; ch++) {
        int cur = ch & 1;
        __syncthreads();                      // vmcnt drained -> buf[cur] ready
        if (ch + 1 < NCH) stage(cur ^ 1, kbase + (ch + 1) * CHUNK);
#pragma unroll
        for (int ct = 0; ct < 2; ct++) {      // 2 code-tiles of 32 per chunk
            int cl = ct * 32 + m;
            short8 bh[4], bl[4];
#pragma unroll
            for (int ks = 0; ks < 4; ks++) {
                int g = ks * 2 + half;
                bh[ks] = *(const short8*)&ebuf[cur][0][g][cl][0];
                bl[ks] = *(const short8*)&ebuf[cur][1][g][cl][0];
            }
            f32x16 acc0 = {};                 // hi.hi + lo.hi
            f32x16 acc1 = {};                 // hi.lo (independent chain)
#pragma unroll
            for (int ks = 0; ks < 4; ks++) {
                acc0 = __builtin_amdgcn_mfma_f32_32x32x16_bf16(ah[ks], bh[ks], acc0, 0, 0, 0);
                acc1 = __builtin_amdgcn_mfma_f32_32x32x16_bf16(ah[ks], bl[ks], acc1, 0, 0, 0);
                acc0 = __builtin_amdgcn_mfma_f32_32x32x16_bf16(al[ks], bh[ks], acc0, 0, 0, 0);
            }

            unsigned slot = (unsigned)(ch * 2 + ct);    // 0..31, uniform (SGPR)
#pragma unroll
            for (int s = 0; s < 16; s++) {
                float c = acc0[s] + acc1[s];
                float dq = fmaf(-2.0f, c, av[s]);       // single fp32 rounding
                unsigned e = (__float_as_uint(dq) << 6) | slot;
                unsigned hi = (p1[s] > e) ? p1[s] : e;  // max
                p1[s] = (p1[s] < e) ? p1[s] : e;        // min
                p2[s] = (p2[s] < hi) ? p2[s] : hi;      // min
            }
        }
    }

    // pack per-lane top2 into u32 scratch: rel(16) | slot(5) | m(5)
    __syncthreads();
    unsigned* sc = (unsigned*)ebuf;          // [128 rows][64 entries] = 32 KB
#pragma unroll
    for (int s = 0; s < 16; s++) {
        int lr = w * 32 + (s & 3) + 8 * (s >> 2) + 4 * half;
        unsigned av26 = __float_as_uint(av[s]) & 0x03FFFFFFu;
#pragma unroll
        for (int j = 0; j < 2; j++) {
            unsigned p = j ? p2[s] : p1[s];
            unsigned dq26 = p >> 6;
            int diff = ((int)((dq26 - av26) << 6)) >> 6;   // sign-extend mod 2^26
            unsigned packed = ((unsigned)(diff + 32768) << 10)
                            | ((p & 63u) << 5) | (unsigned)m;
            sc[lr * 64 + ((2 * m + j + 2 * lr) & 63)] = packed;  // bank-swizzled
        }
    }
    __syncthreads();
    if (t < 128) {
        unsigned b0 = ~0u, b1 = ~0u, b2 = ~0u, b3 = ~0u;
        for (int q = 0; q < 64; q++) {
            unsigned v = sc[t * 64 + ((q + 2 * t) & 63)];
            unsigned m0 = (b0 > v) ? b0 : v;  b0 = (b0 < v) ? b0 : v;
            unsigned m1 = (b1 > m0) ? b1 : m0; b1 = (b1 < m0) ? b1 : m0;
            unsigned m2 = (b2 > m1) ? b2 : m1; b2 = (b2 < m1) ? b2 : m1;
            b3 = (b3 < m2) ? b3 : m2;
        }
        // pcand layout [row][split][4] -> refine reads 256B/row coalesced
        size_t base = (size_t)(n0 + t) * (KSPLIT * 4) + split * 4;
        pcand[base + 0] = b0; pcand[base + 1] = b1;
        pcand[base + 2] = b2; pcand[base + 3] = b3;
    }
}

__device__ inline double wave_sum_d(double p) {
#pragma unroll
    for (int m = 1; m < 64; m <<= 1) {
        int2 u = __builtin_bit_cast(int2, p);
        u.x = __shfl_xor(u.x, m);
        u.y = __shfl_xor(u.y, m);
        p += __builtin_bit_cast(double, u);
    }
    return p;
}

// ---------------- kernel 3: fp64 refinement (exact fp32-grid numerics) --------
__global__ void vq_refine(const float* __restrict__ emb,
                          const float* __restrict__ anorm,
                          const unsigned* __restrict__ pcand,
                          float* __restrict__ out, int* __restrict__ idxfin)
{
    int t = threadIdx.x;
    int lane = t & 63;
    int n = blockIdx.x * 4 + (t >> 6);    // one wave per row

    double zd = (double)g_zt[(size_t)n * 64 + lane];   // coalesced 256B/row
    float av = anorm[n];
    unsigned av_b = __float_as_uint(av);

    // 64 candidates: lane -> (split = lane>>2, j = lane&3), coalesced read
    unsigned v = pcand[(size_t)n * 64 + lane];
    unsigned dqb = av_b + (v >> 10) - 32768u;          // exact reconstruction
    float cd = __uint_as_float(dqb);
    int ck = (lane >> 2) * KPER + (int)((v >> 5) & 31u) * 32 + (int)(v & 31u);

    float mn = cd;
#pragma unroll
    for (int s = 1; s < 64; s <<= 1) mn = fminf(mn, __shfl_xor(mn, s));
    // margin = 16*ulp(av): >> scan noise (~0.05 ulp) + quantization slack
    float margin = __uint_as_float(av_b & 0xFF800000u) * 0x1p-19f;
    bool ok = (cd <= mn + margin);

    unsigned long long msk = __ballot(ok);
    float bd = INFINITY;
    int bk = 0x7fffffff;
    while (msk) {
        int l = __ffsll((unsigned long long)msk) - 1;
        msk &= msk - 1;
        int k = __shfl(ck, l);
        float ev = emb[(size_t)k * EDIM + lane];
        double c64 = wave_sum_d(zd * (double)ev);
        float c32 = (float)c64;
        float dq = av - 2.0f * c32;
        if (dq < bd || (dq == bd && k < bk)) { bd = dq; bk = k; }
    }
    if (lane == 0) {
        idxfin[n] = bk;
        out[OFF_IDX + n] = (float)bk;
        out[OFF_USAGE + bk] = 1.0f;   // benign race: all writers store 1.0f
    }
}

// ---------------- kernel 4: gather z_q + loss + fused finale ------------------
__global__ void vq_gather(const float* __restrict__ z, const float* __restrict__ emb,
                          const int* __restrict__ idxfin, float* __restrict__ out,
                          float* __restrict__ lossacc, unsigned* __restrict__ done)
{
    __shared__ float buf[32][65];
    __shared__ float red[4];
    __shared__ unsigned lastflag;
    int t = threadIdx.x, w = t >> 6, lane = t & 63;
    int n0 = blockIdx.x * 32;              // 256 blocks
    int b = n0 >> 10, hw0 = n0 & 1023;
    for (int rr = 0; rr < 8; rr++) {
        int rl = w * 8 + rr;
        int k = idxfin[n0 + rl];           // broadcast
        buf[rl][lane] = emb[(size_t)k * 64 + lane];   // coalesced 256B row
    }
    __syncthreads();
    float ls = 0.f;
    int hw_i = t & 31, c0 = t >> 5;        // c0 0..7
    for (int cc = 0; cc < 8; cc++) {
        int c = c0 * 8 + cc;
        int o = b * 65536 + c * 1024 + hw0 + hw_i;
        float zq = buf[hw_i][c];
        float zv = z[o];
        out[OFF_ZQ + o] = zq;
        float d = zq - zv;
        ls = fmaf(d, d, ls);
    }
#pragma unroll
    for (int s = 1; s < 64; s <<= 1) ls += __shfl_xor(ls, s);
    if (lane == 0) red[w] = ls;
    __syncthreads();
    if (t == 0) {
        atomicAdd(lossacc, red[0] + red[1] + red[2] + red[3]);
        __threadfence();
        unsigned old = atomicAdd(done, 1u);
        lastflag = (old == 255u) ? 1u : 0u;
    }
    __syncthreads();
    if (lastflag) {                         // last block: scalar outputs
        float s = 0.f;
        for (int i = 0; i < 64; i++) s += out[OFF_USAGE + t + i * 256];
#pragma unroll
        for (int sh = 1; sh < 64; sh <<= 1) s += __shfl_xor(s, sh);
        if (lane == 0) red[w] = s;
        __syncthreads();
        if (t == 0) {
            __threadfence();
            float total = atomicAdd(lossacc, 0.0f);   // coherent read
            float cnt = red[0] + red[1] + red[2] + red[3];
            out[OFF_NUNIQ] = cnt;
            out[OFF_TOTAL] = cnt / 16384.0f;
            out[OFF_LOSS]  = total * 1.25f / 524288.0f;
        }
    }
}

extern "C" void kernel_launch(void* const* d_in, const int* in_sizes, int n_in,
                              void* d_out, int out_size, void* d_ws, size_t ws_size,
                              hipStream_t stream)
{
    const float* z   = (const float*)d_in[0];   // (8,64,32,32)
    const float* emb = (const float*)d_in[1];   // (16384,64)
    float* out = (float*)d_out;
    char* ws = (char*)d_ws;

    float*    anorm   = (float*)ws;                         // 32 KB
    unsigned* pcand   = (unsigned*)(ws + 32768);            // 8192*64*4B = 2 MB
    int*      idxfin  = (int*)(ws + 32768 + 2097152);       // 32 KB
    float*    lossacc = (float*)(ws + 32768 + 2097152 + 32768);
    unsigned* done    = (unsigned*)(ws + 32768 + 2097152 + 32768 + 4);

    vq_split <<<1152, 256, 0, stream>>>(z, emb, anorm, out, lossacc, done);
    vq_mfma  <<<(N_ROWS / 128) * KSPLIT, 256, 0, stream>>>(anorm, pcand);
    vq_refine<<<N_ROWS / 4, 256, 0, stream>>>(emb, anorm, pcand, out, idxfin);
    vq_gather<<<256, 256, 0, stream>>>(z, emb, idxfin, out, lossacc, done);
}

// Round 9
// 156.543 us; speedup vs baseline: 1.2288x; 1.2288x over previous
//
#include <hip/hip_runtime.h>
#include <math.h>

#define N_ROWS 8192
#define N_E    16384
#define EDIM   64
#define KSPLIT 16
#define KPER   1024          // codes per split
#define CHUNK  64            // codes per staged chunk
#define NCH    (KPER/CHUNK)  // 16

// Output layout (concatenated flat, all float32):
#define OFF_ZQ    0
#define OFF_LOSS  524288
#define OFF_IDX   524289
#define OFF_NUNIQ 532481
#define OFF_USAGE 532482
#define OFF_TOTAL 548866

typedef __attribute__((ext_vector_type(8)))  short  short8;
typedef __attribute__((ext_vector_type(8)))  ushort ushort8;
typedef __attribute__((ext_vector_type(4)))  float  f32x4;

// hi/lo bf16 split of codebook and z + fp32 transposed z (recomputed every call)
// 3-term scan error <= ~1e-7 (0.05 grid ulp) -- proven safe rounds 4 & 7.
__device__ ushort g_eh[N_E * EDIM];
__device__ ushort g_el[N_E * EDIM];
__device__ ushort g_zh[N_ROWS * EDIM];
__device__ ushort g_zl[N_ROWS * EDIM];
__device__ float  g_zt[N_ROWS * EDIM];   // z transposed [n][d] for coalesced refine

__device__ __forceinline__ ushort bf16hi(float v) {
    unsigned u = __float_as_uint(v);
    return (ushort)((u + 0x7fffu + ((u >> 16) & 1u)) >> 16);   // RNE
}

// ---------------- kernel 1: hi/lo split of emb & z, anorm, zero side buffers --
__global__ void vq_split(const float* __restrict__ z, const float* __restrict__ emb,
                         float* __restrict__ anorm, float* __restrict__ out,
                         float* __restrict__ lossacc, unsigned* __restrict__ done)
{
    __shared__ float lds[64][129];
    int bid = blockIdx.x, t = threadIdx.x;
    if (bid < 1024) {                       // emb -> g_eh/g_el (float4 vectorized)
        int i = bid * 256 + t;              // 1024*256 float4 = 16384*64 floats
        float4 v = ((const float4*)emb)[i];
        ushort4 h, l;
        h.x = bf16hi(v.x); h.y = bf16hi(v.y);
        h.z = bf16hi(v.z); h.w = bf16hi(v.w);
        l.x = bf16hi(v.x - __uint_as_float((unsigned)h.x << 16));
        l.y = bf16hi(v.y - __uint_as_float((unsigned)h.y << 16));
        l.z = bf16hi(v.z - __uint_as_float((unsigned)h.z << 16));
        l.w = bf16hi(v.w - __uint_as_float((unsigned)h.w << 16));
        ((ushort4*)g_eh)[i] = h;
        ((ushort4*)g_el)[i] = l;
    } else if (bid < 1088) {                // z transpose -> g_zh/g_zl/g_zt + anorm
        int zb = bid - 1024;                // 0..63
        int b = zb >> 3, hw0 = (zb & 7) << 7;
        const float* zp = z + (size_t)b * 65536 + hw0;
        for (int i = 0; i < 32; i++) {
            int j = i * 256 + t;
            int d = j >> 7, hw = j & 127;
            lds[d][hw] = zp[d * 1024 + hw]; // coalesced read
        }
        __syncthreads();
        // 1024 tasks: (hw, octet-of-8-d) -> 16B/32B vector stores, coalesced
        for (int i = 0; i < 4; i++) {
            int task = i * 256 + t;
            int hw = task >> 3, oct = task & 7;
            ushort8 h8, l8; float4 f0, f1;
            float* fp0 = (float*)&f0; float* fp1 = (float*)&f1;
#pragma unroll
            for (int q = 0; q < 8; q++) {
                float v = lds[oct * 8 + q][hw];
                ushort h = bf16hi(v);
                ((ushort*)&h8)[q] = h;
                ((ushort*)&l8)[q] = bf16hi(v - __uint_as_float((unsigned)h << 16));
                if (q < 4) fp0[q] = v; else fp1[q - 4] = v;
            }
            size_t ro = (size_t)(b * 1024 + hw0 + hw) * 64 + oct * 8;
            *(ushort8*)(g_zh + ro) = h8;
            *(ushort8*)(g_zl + ro) = l8;
            *(float4*)(g_zt + ro) = f0;
            *(float4*)(g_zt + ro + 4) = f1;
        }
        if (t < 128) {                      // anorm: fp32 squares, fp64 sum
            double s = 0.0;
            for (int d = 0; d < 64; d++) {
                float v = lds[d][t];
                s += (double)(v * v);
            }
            anorm[b * 1024 + hw0 + t] = (float)s;
        }
    } else {                                // 1088..1151: zero usage (+scalars)
        int i = (bid - 1088) * 256 + t;
        out[OFF_USAGE + i] = 0.f;
        if (bid == 1088 && t == 0) { *lossacc = 0.f; *done = 0u; }
    }
}

// ---------------- kernel 2: 3-term bf16 MFMA scan (16x16x32 tiles) -----------
// dq = fl(av - 2*(zh.eh + zh.el + zl.eh)): error ~1e-7 << 7.6e-6 grid step.
// 16x16x32 shape cuts per-thread state to ~105 regs (32x32 needed 156 ->
// round-8 forced-occupancy spill disaster). launch_bounds(256,4): 4 waves/EU,
// 128-reg budget, no spill expected. LDS 32 KB -> 4 blocks/CU.
// Layouts (HW-verified m89/m91/m120): A[m=lane&15][k=(lane>>4)*8+j];
// B[k=(lane>>4)*8+j][n=lane&15]; C/D col=lane&15, row=(lane>>4)*4+reg.
// Wave owns 32 rows (2 row-tiles) x 16 cols rolling over 64 col-tiles (slots).
// Key32 = dq_bits<<6 | slot(6): order-preserving (dq in [2,256)).
// Scratch/pcand u32: rel(16) | slot(6) | col(4); rel = dq_ulps-av_ulps+32768.
__global__ __launch_bounds__(256, 4) void vq_mfma(const float* __restrict__ anorm,
                                                  unsigned* __restrict__ pcand)
{
    // [dbuf][hi/lo][granule g=k/8][code 0..63][8 bf16] = 32 KB; reused as scratch
    __shared__ __align__(16) ushort ebuf[2][2][8][CHUNK][8];

    const int t = threadIdx.x;
    const int w = t >> 6, lane = t & 63;
    const int rb = blockIdx.x >> 4, split = blockIdx.x & 15;
    const int n0 = rb * 128;
    const int nw = n0 + w * 32;           // wave rows (32)
    const int kbase = split * KPER;
    const int col = lane & 15, quad = lane >> 4;

    // A fragments resident: [row-tile][kstep]
    short8 ah[2][2], al[2][2];
#pragma unroll
    for (int rt = 0; rt < 2; rt++)
#pragma unroll
        for (int s = 0; s < 2; s++) {
            size_t off = (size_t)(nw + rt * 16 + col) * 64 + s * 32 + quad * 8;
            ah[rt][s] = *(const short8*)(g_zh + off);
            al[rt][s] = *(const short8*)(g_zl + off);
        }

    float av[8];                           // [rt*4 + reg]
#pragma unroll
    for (int rt = 0; rt < 2; rt++)
#pragma unroll
        for (int r = 0; r < 4; r++)
            av[rt * 4 + r] = anorm[nw + rt * 16 + quad * 4 + r];

    unsigned p1[8], p2[8];
#pragma unroll
    for (int s = 0; s < 8; s++) { p1[s] = 0xFFFFFFFFu; p2[s] = 0xFFFFFFFFu; }

    // async stage: 16 x 1KB per chunk, 4 per wave
    auto stage = [&](int dbuf, int code0) {
#pragma unroll
        for (int jj = 0; jj < 4; jj++) {
            int id = w * 4 + jj;           // 0..15
            int h = id >> 3, g = id & 7;
            const ushort* src = h ? g_el : g_eh;
            const ushort* ga = src + (size_t)(code0 + lane) * 64 + g * 8;
            __builtin_amdgcn_global_load_lds(
                (const __attribute__((address_space(1))) void*)ga,
                (__attribute__((address_space(3))) void*)&ebuf[dbuf][h][g][0][0],
                16, 0, 0);
        }
    };

    stage(0, kbase);
    for (int ch = 0; ch < NCH; ch++) {
        int cur = ch & 1;
        __syncthreads();                    // vmcnt drained -> buf[cur] ready
        if (ch + 1 < NCH) stage(cur ^ 1, kbase + (ch + 1) * CHUNK);
#pragma unroll
        for (int ct = 0; ct < 4; ct++) {    // 4 col-tiles of 16 per chunk
            int cn = ct * 16 + col;
            f32x4 a0[2] = {{0,0,0,0},{0,0,0,0}};   // hi.hi + lo.hi per row-tile
            f32x4 a1[2] = {{0,0,0,0},{0,0,0,0}};   // hi.lo
#pragma unroll
            for (int s = 0; s < 2; s++) {
                short8 bh = *(const short8*)&ebuf[cur][0][s * 4 + quad][cn][0];
                short8 bl = *(const short8*)&ebuf[cur][1][s * 4 + quad][cn][0];
#pragma unroll
                for (int rt = 0; rt < 2; rt++) {
                    a0[rt] = __builtin_amdgcn_mfma_f32_16x16x32_bf16(ah[rt][s], bh, a0[rt], 0, 0, 0);
                    a1[rt] = __builtin_amdgcn_mfma_f32_16x16x32_bf16(ah[rt][s], bl, a1[rt], 0, 0, 0);
                    a0[rt] = __builtin_amdgcn_mfma_f32_16x16x32_bf16(al[rt][s], bh, a0[rt], 0, 0, 0);
                }
            }
            unsigned slot = (unsigned)(ch * 4 + ct);    // 0..63, uniform
#pragma unroll
            for (int rt = 0; rt < 2; rt++)
#pragma unroll
                for (int r = 0; r < 4; r++) {
                    int s = rt * 4 + r;
                    float c = a0[rt][r] + a1[rt][r];
                    float dq = fmaf(-2.0f, c, av[s]);   // single fp32 rounding
                    unsigned e = (__float_as_uint(dq) << 6) | slot;
                    unsigned hi = (p1[s] > e) ? p1[s] : e;  // max
                    p1[s] = (p1[s] < e) ? p1[s] : e;        // min
                    p2[s] = (p2[s] < hi) ? p2[s] : hi;      // min
                }
        }
    }

    // pack per-lane top2 into u32 scratch: rel(16) | slot(6) | col(4)
    __syncthreads();
    unsigned* sc = (unsigned*)ebuf;        // [128 rows][32 entries] = 16 KB
#pragma unroll
    for (int s = 0; s < 8; s++) {
        int rt = s >> 2, r = s & 3;
        int lr = w * 32 + rt * 16 + quad * 4 + r;
        unsigned av26 = __float_as_uint(av[s]) & 0x03FFFFFFu;
#pragma unroll
        for (int j = 0; j < 2; j++) {
            unsigned p = j ? p2[s] : p1[s];
            unsigned dq26 = p >> 6;
            int diff = ((int)((dq26 - av26) << 6)) >> 6;   // sign-extend mod 2^26
            unsigned packed = ((unsigned)(diff + 32768) << 10)
                            | ((p & 63u) << 4) | (unsigned)col;
            sc[lr * 32 + ((col * 2 + j + lr * 2) & 31)] = packed;  // bank-swizzled
        }
    }
    __syncthreads();
    if (t < 128) {
        unsigned b0 = ~0u, b1 = ~0u, b2 = ~0u, b3 = ~0u;
        for (int q = 0; q < 32; q++) {
            unsigned v = sc[t * 32 + ((q + 2 * t) & 31)];
            unsigned m0 = (b0 > v) ? b0 : v;  b0 = (b0 < v) ? b0 : v;
            unsigned m1 = (b1 > m0) ? b1 : m0; b1 = (b1 < m0) ? b1 : m0;
            unsigned m2 = (b2 > m1) ? b2 : m1; b2 = (b2 < m1) ? b2 : m1;
            b3 = (b3 < m2) ? b3 : m2;
        }
        // pcand layout [row][split][4] -> refine reads 256B/row coalesced
        size_t base = (size_t)(n0 + t) * (KSPLIT * 4) + split * 4;
        pcand[base + 0] = b0; pcand[base + 1] = b1;
        pcand[base + 2] = b2; pcand[base + 3] = b3;
    }
}

__device__ inline double wave_sum_d(double p) {
#pragma unroll
    for (int m = 1; m < 64; m <<= 1) {
        int2 u = __builtin_bit_cast(int2, p);
        u.x = __shfl_xor(u.x, m);
        u.y = __shfl_xor(u.y, m);
        p += __builtin_bit_cast(double, u);
    }
    return p;
}

// ---------------- kernel 3: fp64 refinement (exact fp32-grid numerics) --------
__global__ void vq_refine(const float* __restrict__ emb,
                          const float* __restrict__ anorm,
                          const unsigned* __restrict__ pcand,
                          float* __restrict__ out, int* __restrict__ idxfin)
{
    int t = threadIdx.x;
    int lane = t & 63;
    int n = blockIdx.x * 4 + (t >> 6);    // one wave per row

    double zd = (double)g_zt[(size_t)n * 64 + lane];   // coalesced 256B/row
    float av = anorm[n];
    unsigned av_b = __float_as_uint(av);

    // 64 candidates: lane -> (split = lane>>2, j = lane&3), coalesced read
    unsigned v = pcand[(size_t)n * 64 + lane];
    unsigned dqb = av_b + (v >> 10) - 32768u;          // exact reconstruction
    float cd = __uint_as_float(dqb);
    int ck = (lane >> 2) * KPER + (int)((v >> 4) & 63u) * 16 + (int)(v & 15u);

    float mn = cd;
#pragma unroll
    for (int s = 1; s < 64; s <<= 1) mn = fminf(mn, __shfl_xor(mn, s));
    // margin = 16*ulp(av): >> scan noise (~0.05 ulp) + quantization slack
    float margin = __uint_as_float(av_b & 0xFF800000u) * 0x1p-19f;
    bool ok = (cd <= mn + margin);

    unsigned long long msk = __ballot(ok);
    float bd = INFINITY;
    int bk = 0x7fffffff;
    while (msk) {
        int l = __ffsll((unsigned long long)msk) - 1;
        msk &= msk - 1;
        int k = __shfl(ck, l);
        float ev = emb[(size_t)k * EDIM + lane];
        double c64 = wave_sum_d(zd * (double)ev);
        float c32 = (float)c64;
        float dq = av - 2.0f * c32;
        if (dq < bd || (dq == bd && k < bk)) { bd = dq; bk = k; }
    }
    if (lane == 0) {
        idxfin[n] = bk;
        out[OFF_IDX + n] = (float)bk;
        out[OFF_USAGE + bk] = 1.0f;   // benign race: all writers store 1.0f
    }
}

// ---------------- kernel 4: gather z_q + loss + fused finale ------------------
__global__ void vq_gather(const float* __restrict__ z, const float* __restrict__ emb,
                          const int* __restrict__ idxfin, float* __restrict__ out,
                          float* __restrict__ lossacc, unsigned* __restrict__ done)
{
    __shared__ float buf[32][65];
    __shared__ float red[4];
    __shared__ unsigned lastflag;
    int t = threadIdx.x, w = t >> 6, lane = t & 63;
    int n0 = blockIdx.x * 32;              // 256 blocks
    int b = n0 >> 10, hw0 = n0 & 1023;
    for (int rr = 0; rr < 8; rr++) {
        int rl = w * 8 + rr;
        int k = idxfin[n0 + rl];           // broadcast
        buf[rl][lane] = emb[(size_t)k * 64 + lane];   // coalesced 256B row
    }
    __syncthreads();
    float ls = 0.f;
    int hw_i = t & 31, c0 = t >> 5;        // c0 0..7
    for (int cc = 0; cc < 8; cc++) {
        int c = c0 * 8 + cc;
        int o = b * 65536 + c * 1024 + hw0 + hw_i;
        float zq = buf[hw_i][c];
        float zv = z[o];
        out[OFF_ZQ + o] = zq;
        float d = zq - zv;
        ls = fmaf(d, d, ls);
    }
#pragma unroll
    for (int s = 1; s < 64; s <<= 1) ls += __shfl_xor(ls, s);
    if (lane == 0) red[w] = ls;
    __syncthreads();
    if (t == 0) {
        atomicAdd(lossacc, red[0] + red[1] + red[2] + red[3]);
        __threadfence();
        unsigned old = atomicAdd(done, 1u);
        lastflag = (old == 255u) ? 1u : 0u;
    }
    __syncthreads();
    if (lastflag) {                         // last block: scalar outputs
        float s = 0.f;
        for (int i = 0; i < 64; i++) s += out[OFF_USAGE + t + i * 256];
#pragma unroll
        for (int sh = 1; sh < 64; sh <<= 1) s += __shfl_xor(s, sh);
        if (lane == 0) red[w] = s;
        __syncthreads();
        if (t == 0) {
            __threadfence();
            float total = atomicAdd(lossacc, 0.0f);   // coherent read
            float cnt = red[0] + red[1] + red[2] + red[3];
            out[OFF_NUNIQ] = cnt;
            out[OFF_TOTAL] = cnt / 16384.0f;
            out[OFF_LOSS]  = total * 1.25f / 524288.0f;
        }
    }
}

extern "C" void kernel_launch(void* const* d_in, const int* in_sizes, int n_in,
                              void* d_out, int out_size, void* d_ws, size_t ws_size,
                              hipStream_t stream)
{
    const float* z   = (const float*)d_in[0];   // (8,64,32,32)
    const float* emb = (const float*)d_in[1];   // (16384,64)
    float* out = (float*)d_out;
    char* ws = (char*)d_ws;

    float*    anorm   = (float*)ws;                         // 32 KB
    unsigned* pcand   = (unsigned*)(ws + 32768);            // 8192*64*4B = 2 MB
    int*      idxfin  = (int*)(ws + 32768 + 2097152);       // 32 KB
    float*    lossacc = (float*)(ws + 32768 + 2097152 + 32768);
    unsigned* done    = (unsigned*)(ws + 32768 + 2097152 + 32768 + 4);

    vq_split <<<1152, 256, 0, stream>>>(z, emb, anorm, out, lossacc, done);
    vq_mfma  <<<(N_ROWS / 128) * KSPLIT, 256, 0, stream>>>(anorm, pcand);
    vq_refine<<<N_ROWS / 4, 256, 0, stream>>>(emb, anorm, pcand, out, idxfin);
    vq_gather<<<256, 256, 0, stream>>>(z, emb, idxfin, out, lossacc, done);
}

// Round 11
// 155.993 us; speedup vs baseline: 1.2331x; 1.0035x over previous
//
#include <hip/hip_runtime.h>
#include <math.h>

#define N_ROWS 8192
#define N_E    16384
#define EDIM   64
#define KSPLIT 16
#define KPER   1024          // codes per split
#define CHUNK  64            // codes per staged chunk
#define NCH    (KPER/CHUNK)  // 16

// Output layout (concatenated flat, all float32):
#define OFF_ZQ    0
#define OFF_LOSS  524288
#define OFF_IDX   524289
#define OFF_NUNIQ 532481
#define OFF_USAGE 532482
#define OFF_TOTAL 548866

// s_waitcnt imm encoding (gfx9-family): vmcnt[3:0], expcnt[6:4], lgkmcnt[11:8]
// 0x0F70 = vmcnt(0), expcnt/lgkmcnt unconstrained.
#define WAIT_VM0() __builtin_amdgcn_s_waitcnt(0x0F70)

typedef __attribute__((ext_vector_type(8)))  short  short8;
typedef __attribute__((ext_vector_type(8)))  ushort ushort8;
typedef __attribute__((ext_vector_type(4)))  float  f32x4;

// hi/lo bf16 split of codebook and z + fp32 transposed z (recomputed every call)
// 3-term scan error <= ~1e-7 (0.05 grid ulp) -- proven safe rounds 4/7/9.
__device__ ushort g_eh[N_E * EDIM];
__device__ ushort g_el[N_E * EDIM];
__device__ ushort g_zh[N_ROWS * EDIM];
__device__ ushort g_zl[N_ROWS * EDIM];
__device__ float  g_zt[N_ROWS * EDIM];   // z transposed [n][d] for coalesced refine

__device__ __forceinline__ ushort bf16hi(float v) {
    unsigned u = __float_as_uint(v);
    return (ushort)((u + 0x7fffu + ((u >> 16) & 1u)) >> 16);   // RNE
}

// ---------------- kernel 1: hi/lo split of emb & z, anorm, zero side buffers --
__global__ void vq_split(const float* __restrict__ z, const float* __restrict__ emb,
                         float* __restrict__ anorm, float* __restrict__ out,
                         float* __restrict__ lossacc, unsigned* __restrict__ done)
{
    __shared__ float lds[64][129];
    int bid = blockIdx.x, t = threadIdx.x;
    if (bid < 1024) {                       // emb -> g_eh/g_el (float4 vectorized)
        int i = bid * 256 + t;              // 1024*256 float4 = 16384*64 floats
        float4 v = ((const float4*)emb)[i];
        ushort4 h, l;
        h.x = bf16hi(v.x); h.y = bf16hi(v.y);
        h.z = bf16hi(v.z); h.w = bf16hi(v.w);
        l.x = bf16hi(v.x - __uint_as_float((unsigned)h.x << 16));
        l.y = bf16hi(v.y - __uint_as_float((unsigned)h.y << 16));
        l.z = bf16hi(v.z - __uint_as_float((unsigned)h.z << 16));
        l.w = bf16hi(v.w - __uint_as_float((unsigned)h.w << 16));
        ((ushort4*)g_eh)[i] = h;
        ((ushort4*)g_el)[i] = l;
    } else if (bid < 1088) {                // z transpose -> g_zh/g_zl/g_zt + anorm
        int zb = bid - 1024;                // 0..63
        int b = zb >> 3, hw0 = (zb & 7) << 7;
        const float* zp = z + (size_t)b * 65536 + hw0;
        for (int i = 0; i < 32; i++) {
            int j = i * 256 + t;
            int d = j >> 7, hw = j & 127;
            lds[d][hw] = zp[d * 1024 + hw]; // coalesced read
        }
        __syncthreads();
        // 1024 tasks: (hw, octet-of-8-d) -> 16B/32B vector stores, coalesced
        for (int i = 0; i < 4; i++) {
            int task = i * 256 + t;
            int hw = task >> 3, oct = task & 7;
            ushort8 h8, l8; float4 f0, f1;
            float* fp0 = (float*)&f0; float* fp1 = (float*)&f1;
#pragma unroll
            for (int q = 0; q < 8; q++) {
                float v = lds[oct * 8 + q][hw];
                ushort h = bf16hi(v);
                ((ushort*)&h8)[q] = h;
                ((ushort*)&l8)[q] = bf16hi(v - __uint_as_float((unsigned)h << 16));
                if (q < 4) fp0[q] = v; else fp1[q - 4] = v;
            }
            size_t ro = (size_t)(b * 1024 + hw0 + hw) * 64 + oct * 8;
            *(ushort8*)(g_zh + ro) = h8;
            *(ushort8*)(g_zl + ro) = l8;
            *(float4*)(g_zt + ro) = f0;
            *(float4*)(g_zt + ro + 4) = f1;
        }
        if (t < 128) {                      // anorm: fp32 squares, fp64 sum
            double s = 0.0;
            for (int d = 0; d < 64; d++) {
                float v = lds[d][t];
                s += (double)(v * v);
            }
            anorm[b * 1024 + hw0 + t] = (float)s;
        }
    } else {                                // 1088..1151: zero usage (+scalars)
        int i = (bid - 1088) * 256 + t;
        out[OFF_USAGE + i] = 0.f;
        if (bid == 1088 && t == 0) { *lossacc = 0.f; *done = 0u; }
    }
}

// ---------------- kernel 2: 3-term bf16 MFMA scan (16x16x32 tiles) -----------
// dq = fl(av - 2*(zh.eh + zh.el + zl.eh)): error ~1e-7 << 7.6e-6 grid step.
// NO __launch_bounds__: round 8/9 showed forced budgets (128 regs) spill the
// K-loop (VGPR_Count 64, 24 MB scratch WRITE); round 10's (256,3) failed idx
// -- suspected LDS-DMA/barrier race when the legalizer emits fine-grained
// vmcnt: each wave's ds_reads consume granules staged by OTHER waves'
// global_load_lds, so every wave must drain vmcnt(0) BEFORE s_barrier.
// WAIT_VM0() makes that drain explicit instead of relying on convention.
// Layouts (HW-verified m89/m91/m120): A[m=lane&15][k=(lane>>4)*8+j];
// B[k=(lane>>4)*8+j][n=lane&15]; C/D col=lane&15, row=(lane>>4)*4+reg.
// Wave owns 32 rows (2 row-tiles) x 16 cols rolling over 64 col-tiles (slots).
// Key32 = dq_bits<<6 | slot(6): order-preserving (dq in [2,256)).
// Scratch/pcand u32: rel(16) | slot(6) | col(4); rel = dq_ulps-av_ulps+32768.
__global__ void vq_mfma(const float* __restrict__ anorm,
                        unsigned* __restrict__ pcand)
{
    // [dbuf][hi/lo][granule g=k/8][code 0..63][8 bf16] = 32 KB; reused as scratch
    __shared__ __align__(16) ushort ebuf[2][2][8][CHUNK][8];

    const int t = threadIdx.x;
    const int w = t >> 6, lane = t & 63;
    const int rb = blockIdx.x >> 4, split = blockIdx.x & 15;
    const int n0 = rb * 128;
    const int nw = n0 + w * 32;           // wave rows (32)
    const int kbase = split * KPER;
    const int col = lane & 15, quad = lane >> 4;

    // A fragments resident: [row-tile][kstep]
    short8 ah[2][2], al[2][2];
#pragma unroll
    for (int rt = 0; rt < 2; rt++)
#pragma unroll
        for (int s = 0; s < 2; s++) {
            size_t off = (size_t)(nw + rt * 16 + col) * 64 + s * 32 + quad * 8;
            ah[rt][s] = *(const short8*)(g_zh + off);
            al[rt][s] = *(const short8*)(g_zl + off);
        }

    float av[8];                           // [rt*4 + reg]
#pragma unroll
    for (int rt = 0; rt < 2; rt++)
#pragma unroll
        for (int r = 0; r < 4; r++)
            av[rt * 4 + r] = anorm[nw + rt * 16 + quad * 4 + r];

    unsigned p1[8], p2[8];
#pragma unroll
    for (int s = 0; s < 8; s++) { p1[s] = 0xFFFFFFFFu; p2[s] = 0xFFFFFFFFu; }

    // async stage: 16 x 1KB per chunk, 4 per wave
    auto stage = [&](int dbuf, int code0) {
#pragma unroll
        for (int jj = 0; jj < 4; jj++) {
            int id = w * 4 + jj;           // 0..15
            int h = id >> 3, g = id & 7;
            const ushort* src = h ? g_el : g_eh;
            const ushort* ga = src + (size_t)(code0 + lane) * 64 + g * 8;
            __builtin_amdgcn_global_load_lds(
                (const __attribute__((address_space(1))) void*)ga,
                (__attribute__((address_space(3))) void*)&ebuf[dbuf][h][g][0][0],
                16, 0, 0);
        }
    };

    stage(0, kbase);
    for (int ch = 0; ch < NCH; ch++) {
        int cur = ch & 1;
        WAIT_VM0();                         // drain own LDS-DMA before publishing
        __syncthreads();                    // -> all waves' deposits visible
        if (ch + 1 < NCH) stage(cur ^ 1, kbase + (ch + 1) * CHUNK);
#pragma unroll
        for (int ct = 0; ct < 4; ct++) {    // 4 col-tiles of 16 per chunk
            int cn = ct * 16 + col;
            f32x4 a0[2] = {{0,0,0,0},{0,0,0,0}};   // hi.hi + lo.hi per row-tile
            f32x4 a1[2] = {{0,0,0,0},{0,0,0,0}};   // hi.lo
#pragma unroll
            for (int s = 0; s < 2; s++) {
                short8 bh = *(const short8*)&ebuf[cur][0][s * 4 + quad][cn][0];
                short8 bl = *(const short8*)&ebuf[cur][1][s * 4 + quad][cn][0];
#pragma unroll
                for (int rt = 0; rt < 2; rt++) {
                    a0[rt] = __builtin_amdgcn_mfma_f32_16x16x32_bf16(ah[rt][s], bh, a0[rt], 0, 0, 0);
                    a1[rt] = __builtin_amdgcn_mfma_f32_16x16x32_bf16(ah[rt][s], bl, a1[rt], 0, 0, 0);
                    a0[rt] = __builtin_amdgcn_mfma_f32_16x16x32_bf16(al[rt][s], bh, a0[rt], 0, 0, 0);
                }
            }
            unsigned slot = (unsigned)(ch * 4 + ct);    // 0..63, uniform
#pragma unroll
            for (int rt = 0; rt < 2; rt++)
#pragma unroll
                for (int r = 0; r < 4; r++) {
                    int s = rt * 4 + r;
                    float c = a0[rt][r] + a1[rt][r];
                    float dq = fmaf(-2.0f, c, av[s]);   // single fp32 rounding
                    unsigned e = (__float_as_uint(dq) << 6) | slot;
                    unsigned hi = (p1[s] > e) ? p1[s] : e;  // max
                    p1[s] = (p1[s] < e) ? p1[s] : e;        // min
                    p2[s] = (p2[s] < hi) ? p2[s] : hi;      // min
                }
        }
    }

    // pack per-lane top2 into u32 scratch: rel(16) | slot(6) | col(4)
    WAIT_VM0();
    __syncthreads();
    unsigned* sc = (unsigned*)ebuf;        // [128 rows][32 entries] = 16 KB
#pragma unroll
    for (int s = 0; s < 8; s++) {
        int rt = s >> 2, r = s & 3;
        int lr = w * 32 + rt * 16 + quad * 4 + r;
        unsigned av26 = __float_as_uint(av[s]) & 0x03FFFFFFu;
#pragma unroll
        for (int j = 0; j < 2; j++) {
            unsigned p = j ? p2[s] : p1[s];
            unsigned dq26 = p >> 6;
            int diff = ((int)((dq26 - av26) << 6)) >> 6;   // sign-extend mod 2^26
            unsigned packed = ((unsigned)(diff + 32768) << 10)
                            | ((p & 63u) << 4) | (unsigned)col;
            sc[lr * 32 + ((col * 2 + j + lr * 2) & 31)] = packed;  // bank-swizzled
        }
    }
    __syncthreads();
    if (t < 128) {
        unsigned b0 = ~0u, b1 = ~0u, b2 = ~0u, b3 = ~0u;
        for (int q = 0; q < 32; q++) {
            unsigned v = sc[t * 32 + ((q + 2 * t) & 31)];
            unsigned m0 = (b0 > v) ? b0 : v;  b0 = (b0 < v) ? b0 : v;
            unsigned m1 = (b1 > m0) ? b1 : m0; b1 = (b1 < m0) ? b1 : m0;
            unsigned m2 = (b2 > m1) ? b2 : m1; b2 = (b2 < m1) ? b2 : m1;
            b3 = (b3 < m2) ? b3 : m2;
        }
        // pcand layout [row][split][4] -> refine reads 256B/row coalesced
        size_t base = (size_t)(n0 + t) * (KSPLIT * 4) + split * 4;
        pcand[base + 0] = b0; pcand[base + 1] = b1;
        pcand[base + 2] = b2; pcand[base + 3] = b3;
    }
}

__device__ inline double wave_sum_d(double p) {
#pragma unroll
    for (int m = 1; m < 64; m <<= 1) {
        int2 u = __builtin_bit_cast(int2, p);
        u.x = __shfl_xor(u.x, m);
        u.y = __shfl_xor(u.y, m);
        p += __builtin_bit_cast(double, u);
    }
    return p;
}

// ---------------- kernel 3: fp64 refinement (exact fp32-grid numerics) --------
__global__ void vq_refine(const float* __restrict__ emb,
                          const float* __restrict__ anorm,
                          const unsigned* __restrict__ pcand,
                          float* __restrict__ out, int* __restrict__ idxfin)
{
    int t = threadIdx.x;
    int lane = t & 63;
    int n = blockIdx.x * 4 + (t >> 6);    // one wave per row

    double zd = (double)g_zt[(size_t)n * 64 + lane];   // coalesced 256B/row
    float av = anorm[n];
    unsigned av_b = __float_as_uint(av);

    // 64 candidates: lane -> (split = lane>>2, j = lane&3), coalesced read
    unsigned v = pcand[(size_t)n * 64 + lane];
    unsigned dqb = av_b + (v >> 10) - 32768u;          // exact reconstruction
    float cd = __uint_as_float(dqb);
    int ck = (lane >> 2) * KPER + (int)((v >> 4) & 63u) * 16 + (int)(v & 15u);

    float mn = cd;
#pragma unroll
    for (int s = 1; s < 64; s <<= 1) mn = fminf(mn, __shfl_xor(mn, s));
    // margin = 16*ulp(av): >> scan noise (~0.05 ulp) + quantization slack
    float margin = __uint_as_float(av_b & 0xFF800000u) * 0x1p-19f;
    bool ok = (cd <= mn + margin);

    unsigned long long msk = __ballot(ok);
    float bd = INFINITY;
    int bk = 0x7fffffff;
    while (msk) {
        int l = __ffsll((unsigned long long)msk) - 1;
        msk &= msk - 1;
        int k = __shfl(ck, l);
        float ev = emb[(size_t)k * EDIM + lane];
        double c64 = wave_sum_d(zd * (double)ev);
        float c32 = (float)c64;
        float dq = av - 2.0f * c32;
        if (dq < bd || (dq == bd && k < bk)) { bd = dq; bk = k; }
    }
    if (lane == 0) {
        idxfin[n] = bk;
        out[OFF_IDX + n] = (float)bk;
        out[OFF_USAGE + bk] = 1.0f;   // benign race: all writers store 1.0f
    }
}

// ---------------- kernel 4: gather z_q + loss + fused finale ------------------
__global__ void vq_gather(const float* __restrict__ z, const float* __restrict__ emb,
                          const int* __restrict__ idxfin, float* __restrict__ out,
                          float* __restrict__ lossacc, unsigned* __restrict__ done)
{
    __shared__ float buf[32][65];
    __shared__ float red[4];
    __shared__ unsigned lastflag;
    int t = threadIdx.x, w = t >> 6, lane = t & 63;
    int n0 = blockIdx.x * 32;              // 256 blocks
    int b = n0 >> 10, hw0 = n0 & 1023;
    for (int rr = 0; rr < 8; rr++) {
        int rl = w * 8 + rr;
        int k = idxfin[n0 + rl];           // broadcast
        buf[rl][lane] = emb[(size_t)k * 64 + lane];   // coalesced 256B row
    }
    __syncthreads();
    float ls = 0.f;
    int hw_i = t & 31, c0 = t >> 5;        // c0 0..7
    for (int cc = 0; cc < 8; cc++) {
        int c = c0 * 8 + cc;
        int o = b * 65536 + c * 1024 + hw0 + hw_i;
        float zq = buf[hw_i][c];
        float zv = z[o];
        out[OFF_ZQ + o] = zq;
        float d = zq - zv;
        ls = fmaf(d, d, ls);
    }
#pragma unroll
    for (int s = 1; s < 64; s <<= 1) ls += __shfl_xor(ls, s);
    if (lane == 0) red[w] = ls;
    __syncthreads();
    if (t == 0) {
        atomicAdd(lossacc, red[0] + red[1] + red[2] + red[3]);
        __threadfence();
        unsigned old = atomicAdd(done, 1u);
        lastflag = (old == 255u) ? 1u : 0u;
    }
    __syncthreads();
    if (lastflag) {                         // last block: scalar outputs
        float s = 0.f;
        for (int i = 0; i < 64; i++) s += out[OFF_USAGE + t + i * 256];
#pragma unroll
        for (int sh = 1; sh < 64; sh <<= 1) s += __shfl_xor(s, sh);
        if (lane == 0) red[w] = s;
        __syncthreads();
        if (t == 0) {
            __threadfence();
            float total = atomicAdd(lossacc, 0.0f);   // coherent read
            float cnt = red[0] + red[1] + red[2] + red[3];
            out[OFF_NUNIQ] = cnt;
            out[OFF_TOTAL] = cnt / 16384.0f;
            out[OFF_LOSS]  = total * 1.25f / 524288.0f;
        }
    }
}

extern "C" void kernel_launch(void* const* d_in, const int* in_sizes, int n_in,
                              void* d_out, int out_size, void* d_ws, size_t ws_size,
                              hipStream_t stream)
{
    const float* z   = (const float*)d_in[0];   // (8,64,32,32)
    const float* emb = (const float*)d_in[1];   // (16384,64)
    float* out = (float*)d_out;
    char* ws = (char*)d_ws;

    float*    anorm   = (float*)ws;                         // 32 KB
    unsigned* pcand   = (unsigned*)(ws + 32768);            // 8192*64*4B = 2 MB
    int*      idxfin  = (int*)(ws + 32768 + 2097152);       // 32 KB
    float*    lossacc = (float*)(ws + 32768 + 2097152 + 32768);
    unsigned* done    = (unsigned*)(ws + 32768 + 2097152 + 32768 + 4);

    vq_split <<<1152, 256, 0, stream>>>(z, emb, anorm, out, lossacc, done);
    vq_mfma  <<<(N_ROWS / 128) * KSPLIT, 256, 0, stream>>>(anorm, pcand);
    vq_refine<<<N_ROWS / 4, 256, 0, stream>>>(emb, anorm, pcand, out, idxfin);
    vq_gather<<<256, 256, 0, stream>>>(z, emb, idxfin, out, lossacc, done);
}

// Round 12
// 146.753 us; speedup vs baseline: 1.3108x; 1.0630x over previous
//
#include <hip/hip_runtime.h>
#include <math.h>

#define N_ROWS 8192
#define N_E    16384
#define EDIM   64
#define KSPLIT 16
#define KPER   1024          // codes per split
#define CHUNK  64            // codes per staged chunk
#define NCH    (KPER/CHUNK)  // 16

// Output layout (concatenated flat, all float32):
#define OFF_ZQ    0
#define OFF_LOSS  524288
#define OFF_IDX   524289
#define OFF_NUNIQ 532481
#define OFF_USAGE 532482
#define OFF_TOTAL 548866

// s_waitcnt imm encoding (gfx9-family): vmcnt[3:0], expcnt[6:4], lgkmcnt[11:8]
// 0x0F70 = vmcnt(0), expcnt/lgkmcnt unconstrained.
#define WAIT_VM0() __builtin_amdgcn_s_waitcnt(0x0F70)

typedef __attribute__((ext_vector_type(8)))  short  short8;
typedef __attribute__((ext_vector_type(8)))  ushort ushort8;
typedef __attribute__((ext_vector_type(4)))  float  f32x4;

// hi/lo bf16 split of codebook and z + fp32 transposed z (recomputed every call)
// 3-term scan error <= ~1e-7 (0.05 grid ulp) -- proven safe rounds 4/7/9/11.
__device__ ushort g_eh[N_E * EDIM];
__device__ ushort g_el[N_E * EDIM];
__device__ ushort g_zh[N_ROWS * EDIM];
__device__ ushort g_zl[N_ROWS * EDIM];
__device__ float  g_zt[N_ROWS * EDIM];   // z transposed [n][d] for coalesced refine

__device__ __forceinline__ ushort bf16hi(float v) {
    unsigned u = __float_as_uint(v);
    return (ushort)((u + 0x7fffu + ((u >> 16) & 1u)) >> 16);   // RNE
}

// ---------------- kernel 1: hi/lo split of emb & z, anorm, zero side buffers --
__global__ __launch_bounds__(256) void vq_split(
    const float* __restrict__ z, const float* __restrict__ emb,
    float* __restrict__ anorm, float* __restrict__ out,
    float* __restrict__ lossacc, unsigned* __restrict__ done)
{
    __shared__ float lds[64][129];
    int bid = blockIdx.x, t = threadIdx.x;
    if (bid < 1024) {                       // emb -> g_eh/g_el (float4 vectorized)
        int i = bid * 256 + t;              // 1024*256 float4 = 16384*64 floats
        float4 v = ((const float4*)emb)[i];
        ushort4 h, l;
        h.x = bf16hi(v.x); h.y = bf16hi(v.y);
        h.z = bf16hi(v.z); h.w = bf16hi(v.w);
        l.x = bf16hi(v.x - __uint_as_float((unsigned)h.x << 16));
        l.y = bf16hi(v.y - __uint_as_float((unsigned)h.y << 16));
        l.z = bf16hi(v.z - __uint_as_float((unsigned)h.z << 16));
        l.w = bf16hi(v.w - __uint_as_float((unsigned)h.w << 16));
        ((ushort4*)g_eh)[i] = h;
        ((ushort4*)g_el)[i] = l;
    } else if (bid < 1088) {                // z transpose -> g_zh/g_zl/g_zt + anorm
        int zb = bid - 1024;                // 0..63
        int b = zb >> 3, hw0 = (zb & 7) << 7;
        const float* zp = z + (size_t)b * 65536 + hw0;
        for (int i = 0; i < 32; i++) {
            int j = i * 256 + t;
            int d = j >> 7, hw = j & 127;
            lds[d][hw] = zp[d * 1024 + hw]; // coalesced read
        }
        __syncthreads();
        // 1024 tasks: (hw, octet-of-8-d) -> 16B/32B vector stores, coalesced
        for (int i = 0; i < 4; i++) {
            int task = i * 256 + t;
            int hw = task >> 3, oct = task & 7;
            ushort8 h8, l8; float4 f0, f1;
            float* fp0 = (float*)&f0; float* fp1 = (float*)&f1;
#pragma unroll
            for (int q = 0; q < 8; q++) {
                float v = lds[oct * 8 + q][hw];
                ushort h = bf16hi(v);
                ((ushort*)&h8)[q] = h;
                ((ushort*)&l8)[q] = bf16hi(v - __uint_as_float((unsigned)h << 16));
                if (q < 4) fp0[q] = v; else fp1[q - 4] = v;
            }
            size_t ro = (size_t)(b * 1024 + hw0 + hw) * 64 + oct * 8;
            *(ushort8*)(g_zh + ro) = h8;
            *(ushort8*)(g_zl + ro) = l8;
            *(float4*)(g_zt + ro) = f0;
            *(float4*)(g_zt + ro + 4) = f1;
        }
        if (t < 128) {                      // anorm: fp32 squares, fp64 sum
            double s = 0.0;
            for (int d = 0; d < 64; d++) {
                float v = lds[d][t];
                s += (double)(v * v);
            }
            anorm[b * 1024 + hw0 + t] = (float)s;
        }
    } else {                                // 1088..1151: zero usage (+scalars)
        int i = (bid - 1088) * 256 + t;
        out[OFF_USAGE + i] = 0.f;
        if (bid == 1088 && t == 0) { *lossacc = 0.f; *done = 0u; }
    }
}

// ---------------- kernel 2: 3-term bf16 MFMA scan (16x16x32 tiles) -----------
// dq = fl(av - 2*(zh.eh + zh.el + zl.eh)): error ~1e-7 << 7.6e-6 grid step.
// __launch_bounds__(256) ONLY (flat wgs 256, no waves/EU cap): rounds 8-11
// showed any forced budget <=170 regs -- incl. the no-attribute default,
// which assumes flat wgs 1024 => <=128 unified regs => VGPR_Count 64 --
// spills the K-loop (24 MB scratch WRITE_SIZE). Natural need ~130-160 regs.
// WAIT_VM0 before each barrier: waves consume granules staged by OTHER
// waves' global_load_lds, so every wave must drain vmcnt(0) pre-s_barrier.
// Layouts (HW-verified m89/m91/m120): A[m=lane&15][k=(lane>>4)*8+j];
// B[k=(lane>>4)*8+j][n=lane&15]; C/D col=lane&15, row=(lane>>4)*4+reg.
// Wave owns 32 rows (2 row-tiles) x 16 cols rolling over 64 col-tiles (slots).
// Key32 = dq_bits<<6 | slot(6): order-preserving (dq in [2,256)).
// Scratch/pcand u32: rel(16) | slot(6) | col(4); rel = dq_ulps-av_ulps+32768.
__global__ __launch_bounds__(256) void vq_mfma(const float* __restrict__ anorm,
                                               unsigned* __restrict__ pcand)
{
    // [dbuf][hi/lo][granule g=k/8][code 0..63][8 bf16] = 32 KB; reused as scratch
    __shared__ __align__(16) ushort ebuf[2][2][8][CHUNK][8];

    const int t = threadIdx.x;
    const int w = t >> 6, lane = t & 63;
    const int rb = blockIdx.x >> 4, split = blockIdx.x & 15;
    const int n0 = rb * 128;
    const int nw = n0 + w * 32;           // wave rows (32)
    const int kbase = split * KPER;
    const int col = lane & 15, quad = lane >> 4;

    // A fragments resident: [row-tile][kstep]
    short8 ah[2][2], al[2][2];
#pragma unroll
    for (int rt = 0; rt < 2; rt++)
#pragma unroll
        for (int s = 0; s < 2; s++) {
            size_t off = (size_t)(nw + rt * 16 + col) * 64 + s * 32 + quad * 8;
            ah[rt][s] = *(const short8*)(g_zh + off);
            al[rt][s] = *(const short8*)(g_zl + off);
        }

    float av[8];                           // [rt*4 + reg]
#pragma unroll
    for (int rt = 0; rt < 2; rt++)
#pragma unroll
        for (int r = 0; r < 4; r++)
            av[rt * 4 + r] = anorm[nw + rt * 16 + quad * 4 + r];

    unsigned p1[8], p2[8];
#pragma unroll
    for (int s = 0; s < 8; s++) { p1[s] = 0xFFFFFFFFu; p2[s] = 0xFFFFFFFFu; }

    // async stage: 16 x 1KB per chunk, 4 per wave
    auto stage = [&](int dbuf, int code0) {
#pragma unroll
        for (int jj = 0; jj < 4; jj++) {
            int id = w * 4 + jj;           // 0..15
            int h = id >> 3, g = id & 7;
            const ushort* src = h ? g_el : g_eh;
            const ushort* ga = src + (size_t)(code0 + lane) * 64 + g * 8;
            __builtin_amdgcn_global_load_lds(
                (const __attribute__((address_space(1))) void*)ga,
                (__attribute__((address_space(3))) void*)&ebuf[dbuf][h][g][0][0],
                16, 0, 0);
        }
    };

    stage(0, kbase);
    for (int ch = 0; ch < NCH; ch++) {
        int cur = ch & 1;
        WAIT_VM0();                         // drain own LDS-DMA before publishing
        __syncthreads();                    // -> all waves' deposits visible
        if (ch + 1 < NCH) stage(cur ^ 1, kbase + (ch + 1) * CHUNK);
#pragma unroll
        for (int ct = 0; ct < 4; ct++) {    // 4 col-tiles of 16 per chunk
            int cn = ct * 16 + col;
            f32x4 a0[2] = {{0,0,0,0},{0,0,0,0}};   // hi.hi + lo.hi per row-tile
            f32x4 a1[2] = {{0,0,0,0},{0,0,0,0}};   // hi.lo
#pragma unroll
            for (int s = 0; s < 2; s++) {
                short8 bh = *(const short8*)&ebuf[cur][0][s * 4 + quad][cn][0];
                short8 bl = *(const short8*)&ebuf[cur][1][s * 4 + quad][cn][0];
#pragma unroll
                for (int rt = 0; rt < 2; rt++) {
                    a0[rt] = __builtin_amdgcn_mfma_f32_16x16x32_bf16(ah[rt][s], bh, a0[rt], 0, 0, 0);
                    a1[rt] = __builtin_amdgcn_mfma_f32_16x16x32_bf16(ah[rt][s], bl, a1[rt], 0, 0, 0);
                    a0[rt] = __builtin_amdgcn_mfma_f32_16x16x32_bf16(al[rt][s], bh, a0[rt], 0, 0, 0);
                }
            }
            unsigned slot = (unsigned)(ch * 4 + ct);    // 0..63, uniform
#pragma unroll
            for (int rt = 0; rt < 2; rt++)
#pragma unroll
                for (int r = 0; r < 4; r++) {
                    int s = rt * 4 + r;
                    float c = a0[rt][r] + a1[rt][r];
                    float dq = fmaf(-2.0f, c, av[s]);   // single fp32 rounding
                    unsigned e = (__float_as_uint(dq) << 6) | slot;
                    unsigned hi = (p1[s] > e) ? p1[s] : e;  // max
                    p1[s] = (p1[s] < e) ? p1[s] : e;        // min
                    p2[s] = (p2[s] < hi) ? p2[s] : hi;      // min
                }
        }
    }

    // pack per-lane top2 into u32 scratch: rel(16) | slot(6) | col(4)
    WAIT_VM0();
    __syncthreads();
    unsigned* sc = (unsigned*)ebuf;        // [128 rows][32 entries] = 16 KB
#pragma unroll
    for (int s = 0; s < 8; s++) {
        int rt = s >> 2, r = s & 3;
        int lr = w * 32 + rt * 16 + quad * 4 + r;
        unsigned av26 = __float_as_uint(av[s]) & 0x03FFFFFFu;
#pragma unroll
        for (int j = 0; j < 2; j++) {
            unsigned p = j ? p2[s] : p1[s];
            unsigned dq26 = p >> 6;
            int diff = ((int)((dq26 - av26) << 6)) >> 6;   // sign-extend mod 2^26
            unsigned packed = ((unsigned)(diff + 32768) << 10)
                            | ((p & 63u) << 4) | (unsigned)col;
            sc[lr * 32 + ((col * 2 + j + lr * 2) & 31)] = packed;  // bank-swizzled
        }
    }
    __syncthreads();
    if (t < 128) {
        unsigned b0 = ~0u, b1 = ~0u, b2 = ~0u, b3 = ~0u;
        for (int q = 0; q < 32; q++) {
            unsigned v = sc[t * 32 + ((q + 2 * t) & 31)];
            unsigned m0 = (b0 > v) ? b0 : v;  b0 = (b0 < v) ? b0 : v;
            unsigned m1 = (b1 > m0) ? b1 : m0; b1 = (b1 < m0) ? b1 : m0;
            unsigned m2 = (b2 > m1) ? b2 : m1; b2 = (b2 < m1) ? b2 : m1;
            b3 = (b3 < m2) ? b3 : m2;
        }
        // pcand layout [row][split][4] -> refine reads 256B/row coalesced
        size_t base = (size_t)(n0 + t) * (KSPLIT * 4) + split * 4;
        pcand[base + 0] = b0; pcand[base + 1] = b1;
        pcand[base + 2] = b2; pcand[base + 3] = b3;
    }
}

__device__ inline double wave_sum_d(double p) {
#pragma unroll
    for (int m = 1; m < 64; m <<= 1) {
        int2 u = __builtin_bit_cast(int2, p);
        u.x = __shfl_xor(u.x, m);
        u.y = __shfl_xor(u.y, m);
        p += __builtin_bit_cast(double, u);
    }
    return p;
}

// ---------------- kernel 3: fp64 refinement (exact fp32-grid numerics) --------
__global__ __launch_bounds__(256) void vq_refine(
    const float* __restrict__ emb, const float* __restrict__ anorm,
    const unsigned* __restrict__ pcand,
    float* __restrict__ out, int* __restrict__ idxfin)
{
    int t = threadIdx.x;
    int lane = t & 63;
    int n = blockIdx.x * 4 + (t >> 6);    // one wave per row

    double zd = (double)g_zt[(size_t)n * 64 + lane];   // coalesced 256B/row
    float av = anorm[n];
    unsigned av_b = __float_as_uint(av);

    // 64 candidates: lane -> (split = lane>>2, j = lane&3), coalesced read
    unsigned v = pcand[(size_t)n * 64 + lane];
    unsigned dqb = av_b + (v >> 10) - 32768u;          // exact reconstruction
    float cd = __uint_as_float(dqb);
    int ck = (lane >> 2) * KPER + (int)((v >> 4) & 63u) * 16 + (int)(v & 15u);

    float mn = cd;
#pragma unroll
    for (int s = 1; s < 64; s <<= 1) mn = fminf(mn, __shfl_xor(mn, s));
    // margin = 16*ulp(av): >> scan noise (~0.05 ulp) + quantization slack
    float margin = __uint_as_float(av_b & 0xFF800000u) * 0x1p-19f;
    bool ok = (cd <= mn + margin);

    unsigned long long msk = __ballot(ok);
    float bd = INFINITY;
    int bk = 0x7fffffff;
    while (msk) {
        int l = __ffsll((unsigned long long)msk) - 1;
        msk &= msk - 1;
        int k = __shfl(ck, l);
        float ev = emb[(size_t)k * EDIM + lane];
        double c64 = wave_sum_d(zd * (double)ev);
        float c32 = (float)c64;
        float dq = av - 2.0f * c32;
        if (dq < bd || (dq == bd && k < bk)) { bd = dq; bk = k; }
    }
    if (lane == 0) {
        idxfin[n] = bk;
        out[OFF_IDX + n] = (float)bk;
        out[OFF_USAGE + bk] = 1.0f;   // benign race: all writers store 1.0f
    }
}

// ---------------- kernel 4: gather z_q + loss + fused finale ------------------
__global__ __launch_bounds__(256) void vq_gather(
    const float* __restrict__ z, const float* __restrict__ emb,
    const int* __restrict__ idxfin, float* __restrict__ out,
    float* __restrict__ lossacc, unsigned* __restrict__ done)
{
    __shared__ float buf[32][65];
    __shared__ float red[4];
    __shared__ unsigned lastflag;
    int t = threadIdx.x, w = t >> 6, lane = t & 63;
    int n0 = blockIdx.x * 32;              // 256 blocks
    int b = n0 >> 10, hw0 = n0 & 1023;
    for (int rr = 0; rr < 8; rr++) {
        int rl = w * 8 + rr;
        int k = idxfin[n0 + rl];           // broadcast
        buf[rl][lane] = emb[(size_t)k * 64 + lane];   // coalesced 256B row
    }
    __syncthreads();
    float ls = 0.f;
    int hw_i = t & 31, c0 = t >> 5;        // c0 0..7
    for (int cc = 0; cc < 8; cc++) {
        int c = c0 * 8 + cc;
        int o = b * 65536 + c * 1024 + hw0 + hw_i;
        float zq = buf[hw_i][c];
        float zv = z[o];
        out[OFF_ZQ + o] = zq;
        float d = zq - zv;
        ls = fmaf(d, d, ls);
    }
#pragma unroll
    for (int s = 1; s < 64; s <<= 1) ls += __shfl_xor(ls, s);
    if (lane == 0) red[w] = ls;
    __syncthreads();
    if (t == 0) {
        atomicAdd(lossacc, red[0] + red[1] + red[2] + red[3]);
        __threadfence();
        unsigned old = atomicAdd(done, 1u);
        lastflag = (old == 255u) ? 1u : 0u;
    }
    __syncthreads();
    if (lastflag) {                         // last block: scalar outputs
        float s = 0.f;
        for (int i = 0; i < 64; i++) s += out[OFF_USAGE + t + i * 256];
#pragma unroll
        for (int sh = 1; sh < 64; sh <<= 1) s += __shfl_xor(s, sh);
        if (lane == 0) red[w] = s;
        __syncthreads();
        if (t == 0) {
            __threadfence();
            float total = atomicAdd(lossacc, 0.0f);   // coherent read
            float cnt = red[0] + red[1] + red[2] + red[3];
            out[OFF_NUNIQ] = cnt;
            out[OFF_TOTAL] = cnt / 16384.0f;
            out[OFF_LOSS]  = total * 1.25f / 524288.0f;
        }
    }
}

extern "C" void kernel_launch(void* const* d_in, const int* in_sizes, int n_in,
                              void* d_out, int out_size, void* d_ws, size_t ws_size,
                              hipStream_t stream)
{
    const float* z   = (const float*)d_in[0];   // (8,64,32,32)
    const float* emb = (const float*)d_in[1];   // (16384,64)
    float* out = (float*)d_out;
    char* ws = (char*)d_ws;

    float*    anorm   = (float*)ws;                         // 32 KB
    unsigned* pcand   = (unsigned*)(ws + 32768);            // 8192*64*4B = 2 MB
    int*      idxfin  = (int*)(ws + 32768 + 2097152);       // 32 KB
    float*    lossacc = (float*)(ws + 32768 + 2097152 + 32768);
    unsigned* done    = (unsigned*)(ws + 32768 + 2097152 + 32768 + 4);

    vq_split <<<1152, 256, 0, stream>>>(z, emb, anorm, out, lossacc, done);
    vq_mfma  <<<(N_ROWS / 128) * KSPLIT, 256, 0, stream>>>(anorm, pcand);
    vq_refine<<<N_ROWS / 4, 256, 0, stream>>>(emb, anorm, pcand, out, idxfin);
    vq_gather<<<256, 256, 0, stream>>>(z, emb, idxfin, out, lossacc, done);
}

// Round 14
// 141.803 us; speedup vs baseline: 1.3565x; 1.0349x over previous
//
#include <hip/hip_runtime.h>
#include <math.h>

#define N_ROWS 8192
#define N_E    16384
#define EDIM   64
#define KSPLIT 16
#define KPER   1024          // codes per split
#define CHUNK  64            // codes per staged chunk
#define NCH    (KPER/CHUNK)  // 16

// Output layout (concatenated flat, all float32):
#define OFF_ZQ    0
#define OFF_LOSS  524288
#define OFF_IDX   524289
#define OFF_NUNIQ 532481
#define OFF_USAGE 532482
#define OFF_TOTAL 548866

// s_waitcnt imm encoding (gfx9-family): vmcnt[3:0], expcnt[6:4], lgkmcnt[11:8]
// 0x0F70 = vmcnt(0), expcnt/lgkmcnt unconstrained.
#define WAIT_VM0() __builtin_amdgcn_s_waitcnt(0x0F70)

typedef __attribute__((ext_vector_type(8)))  short  short8;
typedef __attribute__((ext_vector_type(8)))  ushort ushort8;
typedef __attribute__((ext_vector_type(4)))  float  f32x4;

// hi/lo bf16 split of codebook and z + fp32 transposed z (recomputed every call)
// 3-term scan error <= ~1e-7 (0.05 grid ulp) -- proven safe rounds 4/7/9/11/12.
__device__ ushort g_eh[N_E * EDIM];
__device__ ushort g_el[N_E * EDIM];
__device__ ushort g_zh[N_ROWS * EDIM];
__device__ ushort g_zl[N_ROWS * EDIM];
__device__ float  g_zt[N_ROWS * EDIM];   // z transposed [n][d] for coalesced refine

__device__ __forceinline__ ushort bf16hi(float v) {
    unsigned u = __float_as_uint(v);
    return (ushort)((u + 0x7fffu + ((u >> 16) & 1u)) >> 16);   // RNE
}

// ---------------- kernel 1: hi/lo split of emb & z, anorm, zero side buffers --
__global__ __launch_bounds__(256) void vq_split(
    const float* __restrict__ z, const float* __restrict__ emb,
    float* __restrict__ anorm, float* __restrict__ out,
    float* __restrict__ lossacc, unsigned* __restrict__ done)
{
    __shared__ float lds[64][129];
    int bid = blockIdx.x, t = threadIdx.x;
    if (bid < 1024) {                       // emb -> g_eh/g_el (float4 vectorized)
        int i = bid * 256 + t;              // 1024*256 float4 = 16384*64 floats
        float4 v = ((const float4*)emb)[i];
        ushort4 h, l;
        h.x = bf16hi(v.x); h.y = bf16hi(v.y);
        h.z = bf16hi(v.z); h.w = bf16hi(v.w);
        l.x = bf16hi(v.x - __uint_as_float((unsigned)h.x << 16));
        l.y = bf16hi(v.y - __uint_as_float((unsigned)h.y << 16));
        l.z = bf16hi(v.z - __uint_as_float((unsigned)h.z << 16));
        l.w = bf16hi(v.w - __uint_as_float((unsigned)h.w << 16));
        ((ushort4*)g_eh)[i] = h;
        ((ushort4*)g_el)[i] = l;
    } else if (bid < 1088) {                // z transpose -> g_zh/g_zl/g_zt + anorm
        int zb = bid - 1024;                // 0..63
        int b = zb >> 3, hw0 = (zb & 7) << 7;
        const float* zp = z + (size_t)b * 65536 + hw0;
        for (int i = 0; i < 32; i++) {
            int j = i * 256 + t;
            int d = j >> 7, hw = j & 127;
            lds[d][hw] = zp[d * 1024 + hw]; // coalesced read
        }
        __syncthreads();
        // 1024 tasks: (hw, octet-of-8-d) -> 16B/32B vector stores, coalesced
        for (int i = 0; i < 4; i++) {
            int task = i * 256 + t;
            int hw = task >> 3, oct = task & 7;
            ushort8 h8, l8; float4 f0, f1;
            float* fp0 = (float*)&f0; float* fp1 = (float*)&f1;
#pragma unroll
            for (int q = 0; q < 8; q++) {
                float v = lds[oct * 8 + q][hw];
                ushort h = bf16hi(v);
                ((ushort*)&h8)[q] = h;
                ((ushort*)&l8)[q] = bf16hi(v - __uint_as_float((unsigned)h << 16));
                if (q < 4) fp0[q] = v; else fp1[q - 4] = v;
            }
            size_t ro = (size_t)(b * 1024 + hw0 + hw) * 64 + oct * 8;
            *(ushort8*)(g_zh + ro) = h8;
            *(ushort8*)(g_zl + ro) = l8;
            *(float4*)(g_zt + ro) = f0;
            *(float4*)(g_zt + ro + 4) = f1;
        }
        if (t < 128) {                      // anorm: fp32 squares, fp64 sum
            double s = 0.0;
            for (int d = 0; d < 64; d++) {
                float v = lds[d][t];
                s += (double)(v * v);
            }
            anorm[b * 1024 + hw0 + t] = (float)s;
        }
    } else {                                // 1088..1151: zero usage (+scalars)
        int i = (bid - 1088) * 256 + t;
        out[OFF_USAGE + i] = 0.f;
        if (bid == 1088 && t == 0) { *lossacc = 0.f; *done = 0u; }
    }
}

// ---------------- kernel 2: 3-term bf16 MFMA scan (16x16x32 tiles) -----------
// BYTE-IDENTICAL to round 12 (passing): dq = fl(av - 2*(zh.eh+zh.el+zl.eh)),
// error ~1e-7 << 7.6e-6 grid step. __launch_bounds__(256) only (no waves/EU
// cap: forced budgets <=128 regs spill the K-loop -- rounds 8-11). WAIT_VM0
// before each barrier (cross-wave LDS-DMA publish).
// Layouts (HW-verified m89/m91/m120): A[m=lane&15][k=(lane>>4)*8+j];
// B[k=(lane>>4)*8+j][n=lane&15]; C/D col=lane&15, row=(lane>>4)*4+reg.
// Key32 = dq_bits<<6 | slot(6). pcand u32: rel(16)|slot(6)|col(4).
__global__ __launch_bounds__(256) void vq_mfma(const float* __restrict__ anorm,
                                               unsigned* __restrict__ pcand)
{
    // [dbuf][hi/lo][granule g=k/8][code 0..63][8 bf16] = 32 KB; reused as scratch
    __shared__ __align__(16) ushort ebuf[2][2][8][CHUNK][8];

    const int t = threadIdx.x;
    const int w = t >> 6, lane = t & 63;
    const int rb = blockIdx.x >> 4, split = blockIdx.x & 15;
    const int n0 = rb * 128;
    const int nw = n0 + w * 32;           // wave rows (32)
    const int kbase = split * KPER;
    const int col = lane & 15, quad = lane >> 4;

    // A fragments resident: [row-tile][kstep]
    short8 ah[2][2], al[2][2];
#pragma unroll
    for (int rt = 0; rt < 2; rt++)
#pragma unroll
        for (int s = 0; s < 2; s++) {
            size_t off = (size_t)(nw + rt * 16 + col) * 64 + s * 32 + quad * 8;
            ah[rt][s] = *(const short8*)(g_zh + off);
            al[rt][s] = *(const short8*)(g_zl + off);
        }

    float av[8];                           // [rt*4 + reg]
#pragma unroll
    for (int rt = 0; rt < 2; rt++)
#pragma unroll
        for (int r = 0; r < 4; r++)
            av[rt * 4 + r] = anorm[nw + rt * 16 + quad * 4 + r];

    unsigned p1[8], p2[8];
#pragma unroll
    for (int s = 0; s < 8; s++) { p1[s] = 0xFFFFFFFFu; p2[s] = 0xFFFFFFFFu; }

    // async stage: 16 x 1KB per chunk, 4 per wave
    auto stage = [&](int dbuf, int code0) {
#pragma unroll
        for (int jj = 0; jj < 4; jj++) {
            int id = w * 4 + jj;           // 0..15
            int h = id >> 3, g = id & 7;
            const ushort* src = h ? g_el : g_eh;
            const ushort* ga = src + (size_t)(code0 + lane) * 64 + g * 8;
            __builtin_amdgcn_global_load_lds(
                (const __attribute__((address_space(1))) void*)ga,
                (__attribute__((address_space(3))) void*)&ebuf[dbuf][h][g][0][0],
                16, 0, 0);
        }
    };

    stage(0, kbase);
    for (int ch = 0; ch < NCH; ch++) {
        int cur = ch & 1;
        WAIT_VM0();                         // drain own LDS-DMA before publishing
        __syncthreads();                    // -> all waves' deposits visible
        if (ch + 1 < NCH) stage(cur ^ 1, kbase + (ch + 1) * CHUNK);
#pragma unroll
        for (int ct = 0; ct < 4; ct++) {    // 4 col-tiles of 16 per chunk
            int cn = ct * 16 + col;
            f32x4 a0[2] = {{0,0,0,0},{0,0,0,0}};   // hi.hi + lo.hi per row-tile
            f32x4 a1[2] = {{0,0,0,0},{0,0,0,0}};   // hi.lo
#pragma unroll
            for (int s = 0; s < 2; s++) {
                short8 bh = *(const short8*)&ebuf[cur][0][s * 4 + quad][cn][0];
                short8 bl = *(const short8*)&ebuf[cur][1][s * 4 + quad][cn][0];
#pragma unroll
                for (int rt = 0; rt < 2; rt++) {
                    a0[rt] = __builtin_amdgcn_mfma_f32_16x16x32_bf16(ah[rt][s], bh, a0[rt], 0, 0, 0);
                    a1[rt] = __builtin_amdgcn_mfma_f32_16x16x32_bf16(ah[rt][s], bl, a1[rt], 0, 0, 0);
                    a0[rt] = __builtin_amdgcn_mfma_f32_16x16x32_bf16(al[rt][s], bh, a0[rt], 0, 0, 0);
                }
            }
            unsigned slot = (unsigned)(ch * 4 + ct);    // 0..63, uniform
#pragma unroll
            for (int rt = 0; rt < 2; rt++)
#pragma unroll
                for (int r = 0; r < 4; r++) {
                    int s = rt * 4 + r;
                    float c = a0[rt][r] + a1[rt][r];
                    float dq = fmaf(-2.0f, c, av[s]);   // single fp32 rounding
                    unsigned e = (__float_as_uint(dq) << 6) | slot;
                    unsigned hi = (p1[s] > e) ? p1[s] : e;  // max
                    p1[s] = (p1[s] < e) ? p1[s] : e;        // min
                    p2[s] = (p2[s] < hi) ? p2[s] : hi;      // min
                }
        }
    }

    // pack per-lane top2 into u32 scratch: rel(16) | slot(6) | col(4)
    WAIT_VM0();
    __syncthreads();
    unsigned* sc = (unsigned*)ebuf;        // [128 rows][32 entries] = 16 KB
#pragma unroll
    for (int s = 0; s < 8; s++) {
        int rt = s >> 2, r = s & 3;
        int lr = w * 32 + rt * 16 + quad * 4 + r;
        unsigned av26 = __float_as_uint(av[s]) & 0x03FFFFFFu;
#pragma unroll
        for (int j = 0; j < 2; j++) {
            unsigned p = j ? p2[s] : p1[s];
            unsigned dq26 = p >> 6;
            int diff = ((int)((dq26 - av26) << 6)) >> 6;   // sign-extend mod 2^26
            unsigned packed = ((unsigned)(diff + 32768) << 10)
                            | ((p & 63u) << 4) | (unsigned)col;
            sc[lr * 32 + ((col * 2 + j + lr * 2) & 31)] = packed;  // bank-swizzled
        }
    }
    __syncthreads();
    if (t < 128) {
        unsigned b0 = ~0u, b1 = ~0u, b2 = ~0u, b3 = ~0u;
        for (int q = 0; q < 32; q++) {
            unsigned v = sc[t * 32 + ((q + 2 * t) & 31)];
            unsigned m0 = (b0 > v) ? b0 : v;  b0 = (b0 < v) ? b0 : v;
            unsigned m1 = (b1 > m0) ? b1 : m0; b1 = (b1 < m0) ? b1 : m0;
            unsigned m2 = (b2 > m1) ? b2 : m1; b2 = (b2 < m1) ? b2 : m1;
            b3 = (b3 < m2) ? b3 : m2;
        }
        // pcand layout [row][split][4] -> refine reads 256B/row coalesced
        size_t base = (size_t)(n0 + t) * (KSPLIT * 4) + split * 4;
        pcand[base + 0] = b0; pcand[base + 1] = b1;
        pcand[base + 2] = b2; pcand[base + 3] = b3;
    }
}

__device__ __forceinline__ double shfl_xor_d(double p, int m) {
    int2 u = __builtin_bit_cast(int2, p);
    u.x = __shfl_xor(u.x, m);
    u.y = __shfl_xor(u.y, m);
    return __builtin_bit_cast(double, u);
}
__device__ __forceinline__ unsigned long long shfl_xor_u64(unsigned long long p, int m) {
    int2 u = __builtin_bit_cast(int2, p);
    u.x = __shfl_xor(u.x, m);
    u.y = __shfl_xor(u.y, m);
    return __builtin_bit_cast(unsigned long long, u);
}

// ---------------- kernel 3: fp64 refinement, 4 candidates in parallel --------
// One wave per row; 4 candidates at a time, one per 16-lane quarter (4 dims/
// lane fp64 fma chain + 4-level xor tree). d_q = fl32(av - 2*fl32(c64)) --
// same fp32-grid decision metric as rounds 2-12. Selection = u64 min over
// packed (dq_bits, k) -> identical first-index tie-break.
// ROUND-13 BUG FIX: the candidate broadcast shfl must be UNCONDITIONAL --
// ds_bpermute from an inactive source lane is undefined, and the predicated
// form `(lsel>=0) ? __shfl(..) : -1` deactivates quarters with no candidate,
// which can deactivate the SOURCE lane of another quarter's shfl (observed:
// bkey never set -> idx=-1 -> absmax 16384). All lanes now execute the shfl
// with a clamped index; the result is selected afterwards.
__global__ __launch_bounds__(256) void vq_refine(
    const float* __restrict__ emb, const float* __restrict__ anorm,
    const unsigned* __restrict__ pcand,
    float* __restrict__ out, int* __restrict__ idxfin)
{
    int t = threadIdx.x;
    int lane = t & 63;
    int n = blockIdx.x * 4 + (t >> 6);    // one wave per row
    int li = lane & 15;                    // dim group: dims 4*li..4*li+3
    int qd = lane >> 4;                    // quarter 0..3

    // z dims for this lane (each quarter holds a full copy of z), fp64
    float4 zf = *(const float4*)(g_zt + (size_t)n * 64 + li * 4);
    double z0 = (double)zf.x, z1 = (double)zf.y;
    double z2 = (double)zf.z, z3 = (double)zf.w;

    float av = anorm[n];
    unsigned av_b = __float_as_uint(av);

    // 64 candidates: lane -> (split = lane>>2, j = lane&3), coalesced read
    unsigned v = pcand[(size_t)n * 64 + lane];
    unsigned dqb = av_b + (v >> 10) - 32768u;          // exact reconstruction
    float cd = __uint_as_float(dqb);
    int ck = (lane >> 2) * KPER + (int)((v >> 4) & 63u) * 16 + (int)(v & 15u);

    float mn = cd;
#pragma unroll
    for (int s = 1; s < 64; s <<= 1) mn = fminf(mn, __shfl_xor(mn, s));
    // margin = 16*ulp(av): >> scan noise (~0.05 ulp) + quantization slack
    float margin = __uint_as_float(av_b & 0xFF800000u) * 0x1p-19f;
    unsigned long long msk = __ballot(cd <= mn + margin);

    unsigned long long bkey = ~0ull;
    while (msk) {
        int ls[4];
#pragma unroll
        for (int j = 0; j < 4; j++) {
            ls[j] = msk ? (__ffsll((unsigned long long)msk) - 1) : -1;
            if (msk) msk &= msk - 1;
        }
        int lsel = ls[qd];
        int lsafe = (lsel >= 0) ? lsel : 0;
        int kq = __shfl(ck, lsafe);        // UNCONDITIONAL: all 64 lanes active
        int k = (lsel >= 0) ? kq : -1;
        double s = 0.0;
        if (k >= 0) {
            float4 ef = *(const float4*)(emb + (size_t)k * EDIM + li * 4);
            s = fma(z3, (double)ef.w,
                fma(z2, (double)ef.z,
                fma(z1, (double)ef.y, z0 * (double)ef.x)));
        }
        s += shfl_xor_d(s, 1);
        s += shfl_xor_d(s, 2);
        s += shfl_xor_d(s, 4);
        s += shfl_xor_d(s, 8);             // c64 uniform within each quarter
        if (k >= 0) {
            float c32 = (float)s;
            float dq = av - 2.0f * c32;    // same fp32 rounding as rounds 2-12
            unsigned long long key =
                ((unsigned long long)__float_as_uint(dq) << 32) | (unsigned)k;
            bkey = (key < bkey) ? key : bkey;
        }
    }
#pragma unroll
    for (int m = 1; m < 64; m <<= 1) {
        unsigned long long o = shfl_xor_u64(bkey, m);
        bkey = (o < bkey) ? o : bkey;
    }
    if (lane == 0) {
        int bk = (int)(unsigned)(bkey & 0xffffffffu);
        idxfin[n] = bk;
        out[OFF_IDX + n] = (float)bk;
        out[OFF_USAGE + bk] = 1.0f;   // benign race: all writers store 1.0f
    }
}

// ---------------- kernel 4: gather z_q + loss + fused finale ------------------
__global__ __launch_bounds__(256) void vq_gather(
    const float* __restrict__ z, const float* __restrict__ emb,
    const int* __restrict__ idxfin, float* __restrict__ out,
    float* __restrict__ lossacc, unsigned* __restrict__ done)
{
    __shared__ float buf[32][65];
    __shared__ float red[4];
    __shared__ unsigned lastflag;
    int t = threadIdx.x, w = t >> 6, lane = t & 63;
    int n0 = blockIdx.x * 32;              // 256 blocks
    int b = n0 >> 10, hw0 = n0 & 1023;
    for (int rr = 0; rr < 8; rr++) {
        int rl = w * 8 + rr;
        int k = idxfin[n0 + rl];           // broadcast
        buf[rl][lane] = emb[(size_t)k * 64 + lane];   // coalesced 256B row
    }
    __syncthreads();
    float ls = 0.f;
    int hw_i = t & 31, c0 = t >> 5;        // c0 0..7
    for (int cc = 0; cc < 8; cc++) {
        int c = c0 * 8 + cc;
        int o = b * 65536 + c * 1024 + hw0 + hw_i;
        float zq = buf[hw_i][c];
        float zv = z[o];
        out[OFF_ZQ + o] = zq;
        float d = zq - zv;
        ls = fmaf(d, d, ls);
    }
#pragma unroll
    for (int s = 1; s < 64; s <<= 1) ls += __shfl_xor(ls, s);
    if (lane == 0) red[w] = ls;
    __syncthreads();
    if (t == 0) {
        atomicAdd(lossacc, red[0] + red[1] + red[2] + red[3]);
        __threadfence();
        unsigned old = atomicAdd(done, 1u);
        lastflag = (old == 255u) ? 1u : 0u;
    }
    __syncthreads();
    if (lastflag) {                         // last block: scalar outputs
        float s = 0.f;
        for (int i = 0; i < 64; i++) s += out[OFF_USAGE + t + i * 256];
#pragma unroll
        for (int sh = 1; sh < 64; sh <<= 1) s += __shfl_xor(s, sh);
        if (lane == 0) red[w] = s;
        __syncthreads();
        if (t == 0) {
            __threadfence();
            float total = atomicAdd(lossacc, 0.0f);   // coherent read
            float cnt = red[0] + red[1] + red[2] + red[3];
            out[OFF_NUNIQ] = cnt;
            out[OFF_TOTAL] = cnt / 16384.0f;
            out[OFF_LOSS]  = total * 1.25f / 524288.0f;
        }
    }
}

extern "C" void kernel_launch(void* const* d_in, const int* in_sizes, int n_in,
                              void* d_out, int out_size, void* d_ws, size_t ws_size,
                              hipStream_t stream)
{
    const float* z   = (const float*)d_in[0];   // (8,64,32,32)
    const float* emb = (const float*)d_in[1];   // (16384,64)
    float* out = (float*)d_out;
    char* ws = (char*)d_ws;

    float*    anorm   = (float*)ws;                         // 32 KB
    unsigned* pcand   = (unsigned*)(ws + 32768);            // 8192*64*4B = 2 MB
    int*      idxfin  = (int*)(ws + 32768 + 2097152);       // 32 KB
    float*    lossacc = (float*)(ws + 32768 + 2097152 + 32768);
    unsigned* done    = (unsigned*)(ws + 32768 + 2097152 + 32768 + 4);

    vq_split <<<1152, 256, 0, stream>>>(z, emb, anorm, out, lossacc, done);
    vq_mfma  <<<(N_ROWS / 128) * KSPLIT, 256, 0, stream>>>(anorm, pcand);
    vq_refine<<<N_ROWS / 4, 256, 0, stream>>>(emb, anorm, pcand, out, idxfin);
    vq_gather<<<256, 256, 0, stream>>>(z, emb, idxfin, out, lossacc, done);
}